// Round 1
// baseline (584.180 us; speedup 1.0000x reference)
//
#include <hip/hip_runtime.h>
#include <math.h>

// Problem: N=8192 fp32. out = r_inv[:,None] * (a*b + I), r_inv = 1/rowsum(a*b+I), inf->0.
// One block per row: 256 threads x 8 float4 = 8192 floats = one full row.
// Products kept in registers; rowsum via double accumulation (wave shuffle + LDS).

#define NDIM 8192
#define BLOCK 256
#define V4_PER_THREAD (NDIM / 4 / BLOCK)   // 8

__global__ __launch_bounds__(BLOCK) void row_normalize_kernel(
    const float* __restrict__ a,
    const float* __restrict__ b,
    float* __restrict__ out)
{
    const int row = blockIdx.x;
    const int tid = threadIdx.x;

    const float4* __restrict__ a4 = (const float4*)(a + (size_t)row * NDIM);
    const float4* __restrict__ b4 = (const float4*)(b + (size_t)row * NDIM);
    float4* __restrict__ o4 = (float4*)(out + (size_t)row * NDIM);

    float4 prod[V4_PER_THREAD];
    double sum = 0.0;

#pragma unroll
    for (int i = 0; i < V4_PER_THREAD; ++i) {
        const int idx = tid + i * BLOCK;          // coalesced: lane stride 16B
        const float4 av = a4[idx];
        const float4 bv = b4[idx];
        float4 p;
        p.x = av.x * bv.x;
        p.y = av.y * bv.y;
        p.z = av.z * bv.z;
        p.w = av.w * bv.w;
        // identity: mx[row][row] += 1
        const int col0 = idx << 2;
        if ((unsigned)(row - col0) < 4u) {
            if      (row == col0)     p.x += 1.0f;
            else if (row == col0 + 1) p.y += 1.0f;
            else if (row == col0 + 2) p.z += 1.0f;
            else                      p.w += 1.0f;
        }
        prod[i] = p;
        sum += (double)p.x + (double)p.y + (double)p.z + (double)p.w;
    }

    // wave-64 shuffle reduction
#pragma unroll
    for (int off = 32; off > 0; off >>= 1)
        sum += __shfl_down(sum, off, 64);

    __shared__ double wave_sums[BLOCK / 64];
    __shared__ float r_inv_s;
    const int lane = tid & 63;
    const int wave = tid >> 6;
    if (lane == 0) wave_sums[wave] = sum;
    __syncthreads();
    if (tid == 0) {
        double total = wave_sums[0] + wave_sums[1] + wave_sums[2] + wave_sums[3];
        float rs = (float)total;
        float ri = 1.0f / rs;
        if (isinf(ri)) ri = 0.0f;
        r_inv_s = ri;
    }
    __syncthreads();
    const float r_inv = r_inv_s;

#pragma unroll
    for (int i = 0; i < V4_PER_THREAD; ++i) {
        const int idx = tid + i * BLOCK;
        float4 p = prod[i];
        p.x *= r_inv; p.y *= r_inv; p.z *= r_inv; p.w *= r_inv;
        o4[idx] = p;
    }
}

extern "C" void kernel_launch(void* const* d_in, const int* in_sizes, int n_in,
                              void* d_out, int out_size, void* d_ws, size_t ws_size,
                              hipStream_t stream) {
    const float* a = (const float*)d_in[0];   // estimated_adj
    const float* b = (const float*)d_in[1];   // ori
    float* out = (float*)d_out;
    row_normalize_kernel<<<NDIM, BLOCK, 0, stream>>>(a, b, out);
}